// Round 5
// baseline (145.073 us; speedup 1.0000x reference)
//
#include <hip/hip_runtime.h>

#define L_LEN  1024
#define FDIM   16
#define PERIOD 24
#define HDIM   128
#define BATCH  1024
#define DDIM   (L_LEN*FDIM)      // 16384
#define NH3    (3*HDIM)          // 384
#define THALF  12
#define NCLS   10
#define FH     (FDIM*HDIM)       // 2048
#define NLB    16                // l-strip per build_wp block

typedef short bf16x8  __attribute__((ext_vector_type(8)));
typedef short bf16x16 __attribute__((ext_vector_type(16)));
typedef float f32x4   __attribute__((ext_vector_type(4)));
typedef unsigned int u32x4 __attribute__((ext_vector_type(4)));

__device__ __forceinline__ unsigned short f2bf(float f) {
    unsigned int u = __float_as_uint(f);
    u += 0x7FFFu + ((u >> 16) & 1u);           // RNE
    return (unsigned short)(u >> 16);
}
__device__ __forceinline__ float cinv(int p) { return (p < 16) ? (1.0f/43.0f) : (1.0f/42.0f); }

// ---------------- kernel B: fused = bias broadcast + per-phase column sums ----------------
__global__ void init_phase(const float* __restrict__ be0, const float* __restrict__ be1,
                           const float* __restrict__ be2, const float* __restrict__ We1,
                           const float* __restrict__ We2, float* __restrict__ fused,
                           float* __restrict__ u) {
    int idx = blockIdx.x * blockDim.x + threadIdx.x;
    if (idx < BATCH * NH3) {
        int j = idx % NH3;
        float b = (j < HDIM) ? be0[j] : (j < 2*HDIM ? be1[j - HDIM] : be2[j - 2*HDIM]);
        fused[idx] = b;
    }
    if (idx < 2 * PERIOD * FH) {
        int w   = idx / (PERIOD * FH);
        int rem = idx % (PERIOD * FH);
        int p   = rem / FH;
        int fh  = rem % FH;
        const float* W = (w == 0) ? We1 : We2;
        float s = 0.f;
        for (int l = p; l < L_LEN; l += PERIOD) s += W[(size_t)l * FH + fh];
        u[idx] = s;
    }
}

// ---------------- kernel C: build W' (bf16) — register-window version ----------------
__global__ void build_wp(const float* __restrict__ We0, const float* __restrict__ We2,
                         const float* __restrict__ u, unsigned short* __restrict__ Wp) {
    __shared__ unsigned short tile[3][16][NLB][16];   // [mat][h][l][f] = 24 KB
    int f  = threadIdx.x >> 4;
    int hl = threadIdx.x & 15;
    int h  = blockIdx.x * 16 + hl;
    int l0 = blockIdx.y * NLB;
    int fh = f * HDIM + h;
    const float* u1 = u;
    const float* u2 = u + PERIOD * FH;

    // window registers: j = l0-12 .. l0+NLB+12  (NLB+25 values each)
    float w0[NLB + 25], w2[NLB + 25];
    #pragma unroll
    for (int i = 0; i < NLB + 25; ++i) {
        int j = l0 - THALF + i;
        if (j >= 0 && j < L_LEN) {
            w0[i] = We0[(size_t)j * FH + fh];
            w2[i] = We2[(size_t)j * FH + fh];
        } else { w0[i] = 0.f; w2[i] = 0.f; }
    }

    float Sv1 = 0.f, Sv2 = 0.f;
    #pragma unroll
    for (int p = 0; p < PERIOD; ++p) {
        float ci = cinv(p);
        Sv1 += u1[p * FH + fh] * ci;
        Sv2 += u2[p * FH + fh] * ci;
    }

    float s0 = 0.f, s2 = 0.f;
    #pragma unroll
    for (int i = 0; i < 25; ++i) { s0 += w0[i]; s2 += w2[i]; }

    const float inv25 = 1.0f / 25.0f;
    #pragma unroll
    for (int r = 0; r < NLB; ++r) {
        int l = l0 + r;
        float out0 = s0 * inv25;
        float mav1, mav2;
        if (l >= THALF && l < L_LEN - THALF) {
            int pr = (l + THALF) % PERIOD;
            float cr = cinv(pr);
            mav1 = (Sv1 + u1[pr * FH + fh] * cr) * inv25;
            mav2 = (Sv2 + u2[pr * FH + fh] * cr) * inv25;
        } else {
            mav1 = 0.f; mav2 = 0.f;
            #pragma unroll
            for (int dl = -THALF; dl <= THALF; ++dl) {
                int j = l + dl;
                if (j >= 0 && j < L_LEN) {
                    int p = j % PERIOD;
                    float ci = cinv(p);
                    mav1 += u1[p * FH + fh] * ci;
                    mav2 += u2[p * FH + fh] * ci;
                }
            }
            mav1 *= inv25; mav2 *= inv25;
        }
        int   pl  = l % PERIOD;
        float cl  = cinv(pl);
        float v1l = u1[pl * FH + fh] * cl;
        float v2l = u2[pl * FH + fh] * cl;
        float out1 = v1l - mav1;
        float out2 = w2[r + THALF] - s2 * inv25 - v2l + mav2;

        tile[0][hl][r][f] = f2bf(out0);
        tile[1][hl][r][f] = f2bf(out1);
        tile[2][hl][r][f] = f2bf(out2);

        s0 += w0[r + 25] - w0[r];
        s2 += w2[r + 25] - w2[r];
    }
    __syncthreads();

    for (int cid = threadIdx.x; cid < 3 * 16 * NLB; cid += 256) {
        int m  = cid / (16 * NLB);
        int rm = cid % (16 * NLB);
        int h2 = rm / NLB;
        int ll = rm % NLB;
        bf16x16 v = *(const bf16x16*)&tile[m][h2][ll][0];
        *(bf16x16*)&Wp[(size_t)(m * HDIM + blockIdx.x * 16 + h2) * DDIM
                       + (size_t)(l0 + ll) * FDIM] = v;
    }
}

// ---------------- kernel D: fused += x(fp32) @ Wp^T — 1-barrier/step pipeline ----------------
#define GBM 64
#define GBN 128
#define GBK 64
#define GSPLIT 16
#define GKSPL (DDIM / GSPLIT)    // 1024
#define GKST  (GKSPL / GBK)      // 16
#define LDA   72                 // A LDS stride: 144B ≡ 4 dwords mod 32 -> 2-way (free)
#define NWG   (16 * 3 * GSPLIT)  // 768 blocks, %8==0 (bijective XCD swizzle)

__launch_bounds__(256, 3)
__global__ void gemm2(const float* __restrict__ x, const unsigned short* __restrict__ Wp,
                      float* __restrict__ fused) {
    __shared__ unsigned short As[2][GBM * LDA];   // 2 x 9.2 KB
    __shared__ unsigned short Bs[2][GBN * GBK];   // 2 x 16 KB, linear dest, swizzled content
    int bid = blockIdx.x;
    int swz = (bid & 7) * (NWG / 8) + (bid >> 3);
    int bz  = swz / 48;
    int rem = swz % 48;
    int by  = rem / 16;
    int bx  = rem % 16;
    int m0 = bx * GBM, n0 = by * GBN, k0 = bz * GKSPL;
    int tid = threadIdx.x, lane = tid & 63, wave = tid >> 6;
    int wm = wave >> 1, wn = wave & 1;

    // A staging map: thread -> (row = tid>>2, 16-f32 segment = tid&3)
    int arow = tid >> 2, aseg = tid & 3;
    const float* ag = x + (size_t)(m0 + arow) * DDIM + k0 + aseg * 16;
    // B staging map (T2 source-pre-swizzle): lane covers row c*8+(lane>>3), 16B seg
    int brc  = lane >> 3;                       // row within 8-row chunk
    int bsg  = (lane & 7) ^ brc;                // GLOBAL seg feeding LDS seg (lane&7)

    f32x4 Ra[4], Rb[4];
    f32x4 acc[2][4] = {};

    auto aload = [&](f32x4* R, int s) {
        const float* a = ag + s * GBK;
        #pragma unroll
        for (int i = 0; i < 4; ++i) R[i] = *(const f32x4*)(a + 4 * i);
    };
    auto astore = [&](const f32x4* R, int buf) {
        unsigned int w[8];
        #pragma unroll
        for (int t = 0; t < 8; ++t) {
            float lo = R[t >> 1][(t & 1) * 2];
            float hi = R[t >> 1][(t & 1) * 2 + 1];
            asm("v_cvt_pk_bf16_f32 %0, %1, %2" : "=v"(w[t]) : "v"(lo), "v"(hi));
        }
        unsigned short* dst = &As[buf][arow * LDA + aseg * 16];
        u32x4 v0 = {w[0], w[1], w[2], w[3]};
        u32x4 v1 = {w[4], w[5], w[6], w[7]};
        *(u32x4*)dst       = v0;
        *(u32x4*)(dst + 8) = v1;
    };
    auto bstage = [&](int buf, int s) {
        #pragma unroll
        for (int q = 0; q < 4; ++q) {
            int c = wave * 4 + q;                  // 8-row chunk id (0..15)
            const unsigned short* g = Wp + (size_t)(n0 + c * 8 + brc) * DDIM
                                        + k0 + s * GBK + bsg * 8;
            __builtin_amdgcn_global_load_lds(
                (const __attribute__((address_space(1))) void*)g,
                (__attribute__((address_space(3))) void*)&Bs[buf][c * 512], 16, 0, 0);
        }
    };
    int frow = lane & 15, hi4 = lane >> 4;
    auto compute = [&](int buf) {
        #pragma unroll
        for (int ks = 0; ks < 2; ++ks) {
            bf16x8 av[2], bv[4];
            #pragma unroll
            for (int i = 0; i < 2; ++i)
                av[i] = *(const bf16x8*)&As[buf][(wm*32 + i*16 + frow) * LDA + ks*32 + hi4*8];
            #pragma unroll
            for (int j = 0; j < 4; ++j) {
                int rB = wn*64 + j*16 + frow;
                int sL = (ks*4 + hi4) ^ (frow & 7);    // un-swizzle on read
                bv[j] = *(const bf16x8*)&Bs[buf][rB * GBK + sL * 8];
            }
            #pragma unroll
            for (int i = 0; i < 2; ++i)
                #pragma unroll
                for (int j = 0; j < 4; ++j)
                    acc[i][j] = __builtin_amdgcn_mfma_f32_16x16x32_bf16(av[i], bv[j], acc[i][j], 0, 0, 0);
        }
    };

    // prologue: k0,k1 -> regs; B0 staged; A0 written
    aload(Ra, 0); aload(Rb, 1); bstage(0, 0); astore(Ra, 0);
    __syncthreads();

    for (int s2 = 0; s2 < GKST; s2 += 2) {
        {   int s = s2;                                  // even step, bufs 0
            if (s + 1 < GKST) bstage(1, s + 1);
            if (s + 2 < GKST) aload(Ra, s + 2);
            if (s + 1 < GKST) astore(Rb, 1);             // Rb = step s+1 data (1-step-old load)
            compute(0);
            __syncthreads();
        }
        {   int s = s2 + 1;                              // odd step, bufs 1
            if (s + 1 < GKST) bstage(0, s + 1);
            if (s + 2 < GKST) aload(Rb, s + 2);
            if (s + 1 < GKST) astore(Ra, 0);
            compute(1);
            __syncthreads();
        }
    }

    // epilogue: C/D layout col = lane&15, row = (lane>>4)*4 + reg  [m89/m91]
    int orow = (lane >> 4) * 4, ocol = lane & 15;
    #pragma unroll
    for (int i = 0; i < 2; ++i)
        #pragma unroll
        for (int j = 0; j < 4; ++j)
            #pragma unroll
            for (int r = 0; r < 4; ++r)
                atomicAdd(&fused[(size_t)(m0 + wm*32 + i*16 + orow + r) * NH3
                                 + (n0 + wn*64 + j*16 + ocol)], acc[i][j][r]);
}

// ---------------- kernel E: h = relu(fused @ Wf1 + bf1), 4 rows/block ----------------
__global__ void mlp1(const float* __restrict__ fused, const float* __restrict__ Wf1,
                     const float* __restrict__ bf1, float* __restrict__ h) {
    int b = blockIdx.x * 4 + (threadIdx.x >> 7);
    int j = threadIdx.x & 127;
    float acc = bf1[j];
    const float* fr = fused + (size_t)b * NH3;
    #pragma unroll 4
    for (int i = 0; i < NH3; ++i) acc = fmaf(fr[i], Wf1[(size_t)i * HDIM + j], acc);
    h[(size_t)b * HDIM + j] = fmaxf(acc, 0.f);
}

// ---------------- kernel F: out = h @ Wf2 + bf2 ----------------
__global__ void mlp2(const float* __restrict__ h, const float* __restrict__ Wf2,
                     const float* __restrict__ bf2, float* __restrict__ out) {
    int idx = blockIdx.x * blockDim.x + threadIdx.x;
    if (idx >= BATCH * NCLS) return;
    int b = idx / NCLS, c = idx % NCLS;
    float acc = bf2[c];
    const float* hr = h + (size_t)b * HDIM;
    for (int i = 0; i < HDIM; ++i) acc = fmaf(hr[i], Wf2[(size_t)i * NCLS + c], acc);
    out[idx] = acc;
}

extern "C" void kernel_launch(void* const* d_in, const int* in_sizes, int n_in,
                              void* d_out, int out_size, void* d_ws, size_t ws_size,
                              hipStream_t stream) {
    const float* x   = (const float*)d_in[0];
    const float* We0 = (const float*)d_in[1];
    const float* be0 = (const float*)d_in[2];
    const float* We1 = (const float*)d_in[3];
    const float* be1 = (const float*)d_in[4];
    const float* We2 = (const float*)d_in[5];
    const float* be2 = (const float*)d_in[6];
    const float* Wf1 = (const float*)d_in[7];
    const float* bf1 = (const float*)d_in[8];
    const float* Wf2 = (const float*)d_in[9];
    const float* bf2 = (const float*)d_in[10];
    float* out = (float*)d_out;

    char* wsb = (char*)d_ws;
    size_t off = 0;
    unsigned short* Wp = (unsigned short*)(wsb + off); off += (size_t)NH3 * DDIM * sizeof(unsigned short); // 12.6 MB
    float* u     = (float*)(wsb + off); off += (size_t)2 * PERIOD * FH * sizeof(float);                    // 0.39 MB
    float* fused = (float*)(wsb + off); off += (size_t)BATCH * NH3 * sizeof(float);                        // 1.57 MB
    float* hbuf  = (float*)(wsb + off); off += (size_t)BATCH * HDIM * sizeof(float);                       // 0.52 MB

    init_phase<<<(BATCH * NH3 + 255) / 256, 256, 0, stream>>>(be0, be1, be2, We1, We2, fused, u);
    build_wp<<<dim3(8, L_LEN / NLB), 256, 0, stream>>>(We0, We2, u, Wp);
    gemm2<<<NWG, 256, 0, stream>>>(x, Wp, fused);
    mlp1<<<BATCH / 4, 512, 0, stream>>>(fused, Wf1, bf1, hbuf);
    mlp2<<<(BATCH * NCLS + 255) / 256, 256, 0, stream>>>(hbuf, Wf2, bf2, out);
}

// Round 6
// 129.128 us; speedup vs baseline: 1.1235x; 1.1235x over previous
//
#include <hip/hip_runtime.h>

#define L_LEN  1024
#define FDIM   16
#define PERIOD 24
#define HDIM   128
#define BATCH  1024
#define DDIM   (L_LEN*FDIM)      // 16384
#define NH3    (3*HDIM)          // 384
#define THALF  12
#define NCLS   10
#define FH     (FDIM*HDIM)       // 2048
#define NLB    8                 // l-strip per build_wp block

typedef short bf16x8  __attribute__((ext_vector_type(8)));
typedef short bf16x16 __attribute__((ext_vector_type(16)));
typedef float f32x4   __attribute__((ext_vector_type(4)));
typedef unsigned int u32x4 __attribute__((ext_vector_type(4)));

__device__ __forceinline__ unsigned short f2bf(float f) {
    unsigned int u = __float_as_uint(f);
    u += 0x7FFFu + ((u >> 16) & 1u);           // RNE
    return (unsigned short)(u >> 16);
}
__device__ __forceinline__ float cinv(int p) { return (p < 16) ? (1.0f/43.0f) : (1.0f/42.0f); }

// ---------------- kernel B: fused = bias broadcast + per-phase column sums ----------------
__global__ void init_phase(const float* __restrict__ be0, const float* __restrict__ be1,
                           const float* __restrict__ be2, const float* __restrict__ We1,
                           const float* __restrict__ We2, float* __restrict__ fused,
                           float* __restrict__ u) {
    int idx = blockIdx.x * blockDim.x + threadIdx.x;
    if (idx < BATCH * NH3) {
        int j = idx % NH3;
        float b = (j < HDIM) ? be0[j] : (j < 2*HDIM ? be1[j - HDIM] : be2[j - 2*HDIM]);
        fused[idx] = b;
    }
    if (idx < 2 * PERIOD * FH) {
        int w   = idx / (PERIOD * FH);
        int rem = idx % (PERIOD * FH);
        int p   = rem / FH;
        int fh  = rem % FH;
        const float* W = (w == 0) ? We1 : We2;
        float s = 0.f;
        for (int l = p; l < L_LEN; l += PERIOD) s += W[(size_t)l * FH + fh];
        u[idx] = s;
    }
}

// ---------------- kernel C: build W' (bf16) — register-window, spill-free ----------------
// grid (8 h-groups of 16, 128 l-strips of 8); block 256 = (f = tid>>4) x (h = tid&15).
// launch_bounds lifts the default 1024-thread VGPR cap (64) that forced scratch spills.
__launch_bounds__(256, 3)
__global__ void build_wp(const float* __restrict__ We0, const float* __restrict__ We2,
                         const float* __restrict__ u, unsigned short* __restrict__ Wp) {
    // [mat][l][h][f+pad]: write dw-addr = hl*9 + f/2 -> gcd(9,32)=1 -> conflict-free u16 writes
    __shared__ unsigned short tile[3][NLB][16][18];   // 13.8 KB
    int f  = threadIdx.x >> 4;
    int hl = threadIdx.x & 15;
    int h  = blockIdx.x * 16 + hl;
    int l0 = blockIdx.y * NLB;
    int fh = f * HDIM + h;
    const float* u1 = u;
    const float* u2 = u + PERIOD * FH;

    // window registers: j = l0-12 .. l0+NLB+12  (NLB+25 = 33 values each)
    float w0[NLB + 25], w2[NLB + 25];
    #pragma unroll
    for (int i = 0; i < NLB + 25; ++i) {
        int j = l0 - THALF + i;
        if (j >= 0 && j < L_LEN) {
            w0[i] = We0[(size_t)j * FH + fh];
            w2[i] = We2[(size_t)j * FH + fh];
        } else { w0[i] = 0.f; w2[i] = 0.f; }
    }

    float Sv1 = 0.f, Sv2 = 0.f;
    #pragma unroll
    for (int p = 0; p < PERIOD; ++p) {               // 48 independent L2-hot loads
        float ci = cinv(p);
        Sv1 += u1[p * FH + fh] * ci;
        Sv2 += u2[p * FH + fh] * ci;
    }

    float s0 = 0.f, s2 = 0.f;
    #pragma unroll
    for (int i = 0; i < 25; ++i) { s0 += w0[i]; s2 += w2[i]; }

    const float inv25 = 1.0f / 25.0f;
    #pragma unroll
    for (int r = 0; r < NLB; ++r) {
        int l = l0 + r;
        float out0 = s0 * inv25;                     // (T We0)[l]
        float mav1, mav2;
        if (l >= THALF && l < L_LEN - THALF) {       // interior: Sv + repeat phase (l+12)%24
            int pr = (l + THALF) % PERIOD;
            float cr = cinv(pr);
            mav1 = (Sv1 + u1[pr * FH + fh] * cr) * inv25;
            mav2 = (Sv2 + u2[pr * FH + fh] * cr) * inv25;
        } else {                                     // edge strips only
            mav1 = 0.f; mav2 = 0.f;
            #pragma unroll
            for (int dl = -THALF; dl <= THALF; ++dl) {
                int j = l + dl;
                if (j >= 0 && j < L_LEN) {
                    int p = j % PERIOD;
                    float ci = cinv(p);
                    mav1 += u1[p * FH + fh] * ci;
                    mav2 += u2[p * FH + fh] * ci;
                }
            }
            mav1 *= inv25; mav2 *= inv25;
        }
        int   pl  = l % PERIOD;
        float cl  = cinv(pl);
        float v1l = u1[pl * FH + fh] * cl;
        float v2l = u2[pl * FH + fh] * cl;
        float out1 = v1l - mav1;                                      // S^T We1
        float out2 = w2[r + THALF] - s2 * inv25 - v2l + mav2;         // (I-T-S)^T We2

        tile[0][r][hl][f] = f2bf(out0);
        tile[1][r][hl][f] = f2bf(out1);
        tile[2][r][hl][f] = f2bf(out2);

        s0 += w0[r + 25] - w0[r];                    // register-only slide
        s2 += w2[r + 25] - w2[r];
    }
    __syncthreads();

    // read-out: 384 chunks; u32x8 gather (4B-aligned at 36B stride), bf16x16 coalesced store
    {
        int cid = threadIdx.x;                       // 256 threads, 384 chunks
        #pragma unroll
        for (int pass = 0; pass < 2; ++pass, cid += 256) {
            if (cid < 3 * 16 * NLB) {
                int m  = cid / (16 * NLB);
                int rm = cid % (16 * NLB);
                int h2 = rm / NLB;
                int ll = rm % NLB;
                const unsigned int* src = (const unsigned int*)&tile[m][ll][h2][0];
                union { unsigned int d[8]; bf16x16 v; } cvt;
                #pragma unroll
                for (int i = 0; i < 8; ++i) cvt.d[i] = src[i];
                *(bf16x16*)&Wp[(size_t)(m * HDIM + blockIdx.x * 16 + h2) * DDIM
                               + (size_t)(l0 + ll) * FDIM] = cvt.v;
            }
        }
    }
}

// ---------------- kernel D: fused += x(fp32) @ Wp^T — 1-barrier/step pipeline ----------------
#define GBM 64
#define GBN 128
#define GBK 64
#define GSPLIT 16
#define GKSPL (DDIM / GSPLIT)    // 1024
#define GKST  (GKSPL / GBK)      // 16
#define LDA   72                 // A LDS stride: 144B ≡ 4 dwords mod 32 -> 2-way (free)
#define NWG   (16 * 3 * GSPLIT)  // 768 blocks, %8==0 (bijective XCD swizzle)

__launch_bounds__(256, 3)
__global__ void gemm2(const float* __restrict__ x, const unsigned short* __restrict__ Wp,
                      float* __restrict__ fused) {
    __shared__ unsigned short As[2][GBM * LDA];   // 2 x 9.2 KB
    __shared__ unsigned short Bs[2][GBN * GBK];   // 2 x 16 KB, linear dest, swizzled content
    int bid = blockIdx.x;
    int swz = (bid & 7) * (NWG / 8) + (bid >> 3);
    int bz  = swz / 48;
    int rem = swz % 48;
    int by  = rem / 16;
    int bx  = rem % 16;
    int m0 = bx * GBM, n0 = by * GBN, k0 = bz * GKSPL;
    int tid = threadIdx.x, lane = tid & 63, wave = tid >> 6;
    int wm = wave >> 1, wn = wave & 1;

    int arow = tid >> 2, aseg = tid & 3;
    const float* ag = x + (size_t)(m0 + arow) * DDIM + k0 + aseg * 16;
    int brc  = lane >> 3;                       // row within 8-row chunk
    int bsg  = (lane & 7) ^ brc;                // T2 source-pre-swizzle

    f32x4 Ra[4], Rb[4];
    f32x4 acc[2][4] = {};

    auto aload = [&](f32x4* R, int s) {
        const float* a = ag + s * GBK;
        #pragma unroll
        for (int i = 0; i < 4; ++i) R[i] = *(const f32x4*)(a + 4 * i);
    };
    auto astore = [&](const f32x4* R, int buf) {
        unsigned int w[8];
        #pragma unroll
        for (int t = 0; t < 8; ++t) {
            float lo = R[t >> 1][(t & 1) * 2];
            float hi = R[t >> 1][(t & 1) * 2 + 1];
            asm("v_cvt_pk_bf16_f32 %0, %1, %2" : "=v"(w[t]) : "v"(lo), "v"(hi));
        }
        unsigned short* dst = &As[buf][arow * LDA + aseg * 16];
        u32x4 v0 = {w[0], w[1], w[2], w[3]};
        u32x4 v1 = {w[4], w[5], w[6], w[7]};
        *(u32x4*)dst       = v0;
        *(u32x4*)(dst + 8) = v1;
    };
    auto bstage = [&](int buf, int s) {
        #pragma unroll
        for (int q = 0; q < 4; ++q) {
            int c = wave * 4 + q;                  // 8-row chunk id (0..15)
            const unsigned short* g = Wp + (size_t)(n0 + c * 8 + brc) * DDIM
                                        + k0 + s * GBK + bsg * 8;
            __builtin_amdgcn_global_load_lds(
                (const __attribute__((address_space(1))) void*)g,
                (__attribute__((address_space(3))) void*)&Bs[buf][c * 512], 16, 0, 0);
        }
    };
    int frow = lane & 15, hi4 = lane >> 4;
    auto compute = [&](int buf) {
        #pragma unroll
        for (int ks = 0; ks < 2; ++ks) {
            bf16x8 av[2], bv[4];
            #pragma unroll
            for (int i = 0; i < 2; ++i)
                av[i] = *(const bf16x8*)&As[buf][(wm*32 + i*16 + frow) * LDA + ks*32 + hi4*8];
            #pragma unroll
            for (int j = 0; j < 4; ++j) {
                int rB = wn*64 + j*16 + frow;
                int sL = (ks*4 + hi4) ^ (frow & 7);    // un-swizzle on read
                bv[j] = *(const bf16x8*)&Bs[buf][rB * GBK + sL * 8];
            }
            #pragma unroll
            for (int i = 0; i < 2; ++i)
                #pragma unroll
                for (int j = 0; j < 4; ++j)
                    acc[i][j] = __builtin_amdgcn_mfma_f32_16x16x32_bf16(av[i], bv[j], acc[i][j], 0, 0, 0);
        }
    };

    aload(Ra, 0); aload(Rb, 1); bstage(0, 0); astore(Ra, 0);
    __syncthreads();

    for (int s2 = 0; s2 < GKST; s2 += 2) {
        {   int s = s2;                                  // even step, bufs 0
            if (s + 1 < GKST) bstage(1, s + 1);
            if (s + 2 < GKST) aload(Ra, s + 2);
            if (s + 1 < GKST) astore(Rb, 1);
            compute(0);
            __syncthreads();
        }
        {   int s = s2 + 1;                              // odd step, bufs 1
            if (s + 1 < GKST) bstage(0, s + 1);
            if (s + 2 < GKST) aload(Rb, s + 2);
            if (s + 1 < GKST) astore(Ra, 0);
            compute(1);
            __syncthreads();
        }
    }

    int orow = (lane >> 4) * 4, ocol = lane & 15;   // C/D: col=lane&15, row=(lane>>4)*4+r
    #pragma unroll
    for (int i = 0; i < 2; ++i)
        #pragma unroll
        for (int j = 0; j < 4; ++j)
            #pragma unroll
            for (int r = 0; r < 4; ++r)
                atomicAdd(&fused[(size_t)(m0 + wm*32 + i*16 + orow + r) * NH3
                                 + (n0 + wn*64 + j*16 + ocol)], acc[i][j][r]);
}

// ---------------- kernel E: h = relu(fused @ Wf1 + bf1), 4 rows/block ----------------
__global__ void mlp1(const float* __restrict__ fused, const float* __restrict__ Wf1,
                     const float* __restrict__ bf1, float* __restrict__ h) {
    int b = blockIdx.x * 4 + (threadIdx.x >> 7);
    int j = threadIdx.x & 127;
    float acc = bf1[j];
    const float* fr = fused + (size_t)b * NH3;
    #pragma unroll 4
    for (int i = 0; i < NH3; ++i) acc = fmaf(fr[i], Wf1[(size_t)i * HDIM + j], acc);
    h[(size_t)b * HDIM + j] = fmaxf(acc, 0.f);
}

// ---------------- kernel F: out = h @ Wf2 + bf2 ----------------
__global__ void mlp2(const float* __restrict__ h, const float* __restrict__ Wf2,
                     const float* __restrict__ bf2, float* __restrict__ out) {
    int idx = blockIdx.x * blockDim.x + threadIdx.x;
    if (idx >= BATCH * NCLS) return;
    int b = idx / NCLS, c = idx % NCLS;
    float acc = bf2[c];
    const float* hr = h + (size_t)b * HDIM;
    for (int i = 0; i < HDIM; ++i) acc = fmaf(hr[i], Wf2[(size_t)i * NCLS + c], acc);
    out[idx] = acc;
}

extern "C" void kernel_launch(void* const* d_in, const int* in_sizes, int n_in,
                              void* d_out, int out_size, void* d_ws, size_t ws_size,
                              hipStream_t stream) {
    const float* x   = (const float*)d_in[0];
    const float* We0 = (const float*)d_in[1];
    const float* be0 = (const float*)d_in[2];
    const float* We1 = (const float*)d_in[3];
    const float* be1 = (const float*)d_in[4];
    const float* We2 = (const float*)d_in[5];
    const float* be2 = (const float*)d_in[6];
    const float* Wf1 = (const float*)d_in[7];
    const float* bf1 = (const float*)d_in[8];
    const float* Wf2 = (const float*)d_in[9];
    const float* bf2 = (const float*)d_in[10];
    float* out = (float*)d_out;

    char* wsb = (char*)d_ws;
    size_t off = 0;
    unsigned short* Wp = (unsigned short*)(wsb + off); off += (size_t)NH3 * DDIM * sizeof(unsigned short); // 12.6 MB
    float* u     = (float*)(wsb + off); off += (size_t)2 * PERIOD * FH * sizeof(float);                    // 0.39 MB
    float* fused = (float*)(wsb + off); off += (size_t)BATCH * NH3 * sizeof(float);                        // 1.57 MB
    float* hbuf  = (float*)(wsb + off); off += (size_t)BATCH * HDIM * sizeof(float);                       // 0.52 MB

    init_phase<<<(BATCH * NH3 + 255) / 256, 256, 0, stream>>>(be0, be1, be2, We1, We2, fused, u);
    build_wp<<<dim3(8, L_LEN / NLB), 256, 0, stream>>>(We0, We2, u, Wp);
    gemm2<<<NWG, 256, 0, stream>>>(x, Wp, fused);
    mlp1<<<BATCH / 4, 512, 0, stream>>>(fused, Wf1, bf1, hbuf);
    mlp2<<<(BATCH * NCLS + 255) / 256, 256, 0, stream>>>(hbuf, Wf2, bf2, out);
}